// Round 12
// baseline (518.167 us; speedup 1.0000x reference)
//
#include <hip/hip_runtime.h>

typedef short bf16x8 __attribute__((ext_vector_type(8)));
typedef float f32x4  __attribute__((ext_vector_type(4)));
typedef unsigned short u16;

static __device__ __forceinline__ u16 f2bf(float f) {
    unsigned int u = __builtin_bit_cast(unsigned int, f);
    u += 0x7FFFu + ((u >> 16) & 1u);   // round-to-nearest-even
    return (u16)(u >> 16);
}

static __device__ __forceinline__ void gload_lds16(const void* g, void* l) {
    __builtin_amdgcn_global_load_lds((const __attribute__((address_space(1))) void*)g,
                                     (__attribute__((address_space(3))) void*)l, 16, 0, 0);
}

// ---------------- Kernel 1: demodulate + convert weights to bf16 -------------
// wn[((tap*4 + cc)*128 + co)*32 + ci_in_chunk]  == kstep-major [k108][co128][ci32]
__global__ __launch_bounds__(256) void prep_w_k(const float* __restrict__ w,
                                                u16* __restrict__ wn) {
    const int co = blockIdx.x;
    const int t  = threadIdx.x;
    const float* wc = w + co * 3456;
    float s = 0.f;
    for (int i = t; i < 3456; i += 256) { float v = wc[i]; s += v * v; }
#pragma unroll
    for (int off = 32; off; off >>= 1) s += __shfl_down(s, off);
    __shared__ float red[4];
    __shared__ float dsh;
    if ((t & 63) == 0) red[t >> 6] = s;
    __syncthreads();
    if (t == 0) dsh = rsqrtf(red[0] + red[1] + red[2] + red[3] + 1e-8f);
    __syncthreads();
    const float d = dsh;
    for (int i = t; i < 3456; i += 256) {
        int ci = i / 27, tap = i - ci * 27;
        float v = wc[i] * d;
        wn[((tap * 4 + (ci >> 5)) * 128 + co) * 32 + (ci & 31)] = f2bf(v);
    }
}

// ---------------- Kernel 2: transpose x -> channels-grouped bf16 -------------
// xt[((b*16 + g)*32768 + d*1024 + h*32 + w)*8 + j] = bf16(x[b][g*8+j][d][h][w])
__global__ __launch_bounds__(256) void xpose_k(const float* __restrict__ x,
                                               u16* __restrict__ xt) {
    const int bid = blockIdx.x;
    const int b = bid >> 10, d = (bid >> 5) & 31, h = bid & 31;
    const int t = threadIdx.x;
    const int w = t & 31, cg = t >> 5;
    const int base_dhw = d * 1024 + h * 32 + w;
#pragma unroll
    for (int r = 0; r < 2; ++r) {
        int g = cg + r * 8;
        const float* src = x + ((size_t)(b * 128 + g * 8) << 15) + base_dhw;
        bf16x8 pk;
#pragma unroll
        for (int j = 0; j < 8; ++j) pk[j] = (short)f2bf(src[(size_t)j << 15]);
        *(bf16x8*)&xt[((size_t)((b * 16 + g) << 15) + base_dhw) * 8] = pk;
    }
}

// ---------------- Kernel 3: conv3d — w global->reg dbuf, x-only ring-3 -------
// 512 thr = 8 waves (4 M-slices x 2 co-halves). Tile M=256 (d2,h4,w32), N=128.
// (512,2): 256-VGPR budget; expect ~110 VGPR -> 2 blocks/CU possible (LDS 48KB).
// LDS = x ring only: 3 x 16 KB. Per step k:
//   WLOAD w(k+1) global->reg (4x dwordx4, L1/L2 broadcast)   [separate pipe]
//   RDFRAG x(k+1) from buf (k+1)%3 (4x ds_read_b128)
//   DO_STAGE x(k+3) -> buf k%3 (2x global_load_lds)
//   MFMA frags(k) (all-reg operands)
//   lgkmcnt(0); vmcnt(2) [retire w(k+1)+stx(k+2), stx(k+3) flies]; s_barrier
// LDS/step: 48 KB (was 88) -> MFMA becomes top pipe (621 vs 565 cyc).
#define KSX 1048576   // shorts: x advance per k-step (4 groups * 32768 * 8)
#define KSW 4096      // shorts: wn advance per k-step
#define RB  8192      // shorts: ring stride (16 KB x)
__global__ __launch_bounds__(512, 2) void conv_mx(
    const u16* __restrict__ wsb, const float* __restrict__ bias,
    float* __restrict__ out) {
    __shared__ __align__(16) u16 lds[3 * RB];     // 49152 B
    const u16* xt = wsb + 524288;
    const u16* wn = wsb + 512;
    const u16* zp = wsb;                          // zero page (memset)

    const int t = threadIdx.x, lane = t & 63, wid = t >> 6;
    const int ll = lane & 15, g = lane >> 4;
    const int mslice = wid >> 1, ncol = wid & 1;

    int wg = ((blockIdx.x & 7) << 7) | (blockIdx.x >> 3);   // XCD swizzle
    const int b = wg >> 7, dt = (wg >> 3) & 15, ht = wg & 7;
    const int d0 = dt * 2, h0 = ht * 4;

    // loop-invariant ds_read offset (shorts, within ring buffer)
    const int pos0 = mslice * 64 + ll;
    const int xro = pos0 * 32 + ((g ^ ((pos0 >> 1) & 3)) * 8);

    // w global-load base: lane (ll,g) holds co=ncol*64+nf*16+ll, ci=g*8..+8
    const u16* wptr = wn + (ncol * 64 + ll) * 32 + g * 8;

    // x staging lane constants (2 gload_lds per thread per k-step)
    const int posA = wid * 32 + (lane >> 2);
    const int slot = lane & 3;
    const int pdA = posA >> 7, phA = (posA >> 5) & 3, wA = posA & 31;
    const int gA = slot ^ ((posA >> 1) & 3);

    f32x4 acc[4][4];
#pragma unroll
    for (int i = 0; i < 4; ++i)
#pragma unroll
        for (int j = 0; j < 4; ++j) acc[i][j] = (f32x4){0.f, 0.f, 0.f, 0.f};

    // staging cursor
    int od_s = 0, oh_s = 0, ow_s = 0, cc_s = 0;
    const u16* xsA = xt; bool okA = false, okB = false;

    bf16x8 xa[4], wa[4], xb[4], wb[4];   // frag double-buffer (x from LDS, w from global)

#define WLOAD(WF) { \
    _Pragma("unroll") for (int nf = 0; nf < 4; ++nf) \
        WF[nf] = *(const bf16x8*)&wptr[nf * 512]; \
    wptr += KSW; }

#define DO_STAGE(SB) { \
    if (cc_s == 0) { \
        int Dx = d0 + pdA - 1 + od_s, Hx = h0 + phA - 1 + oh_s, Wx = wA - 1 + ow_s; \
        bool dh_ = ((unsigned)Dx < 32u) && ((unsigned)Hx < 32u); \
        okA = dh_ && ((unsigned)Wx < 32u); \
        okB = dh_ && (Wx < 16); \
        xsA = xt + (long)((b * 16 + gA) * 32768 + Dx * 1024 + Hx * 32 + Wx) * 8; } \
    gload_lds16(okA ? (const void*)xsA : (const void*)zp, (void*)&lds[(SB)*RB + wid*1024]); \
    gload_lds16(okB ? (const void*)(xsA + 128) : (const void*)zp, (void*)&lds[(SB)*RB + wid*1024 + 512]); \
    xsA += KSX; \
    if (++cc_s == 4) { cc_s = 0; \
        if (++ow_s == 3) { ow_s = 0; if (++oh_s == 3) { oh_s = 0; ++od_s; } } } }

#define RDFRAG(RD, XF) { \
    _Pragma("unroll") for (int mf = 0; mf < 4; ++mf) \
        XF[mf] = *(const bf16x8*)&lds[(RD)*RB + xro + mf * 512]; }

#define MFMACL(XF, WF) { \
    __builtin_amdgcn_s_setprio(1); \
    _Pragma("unroll") for (int mf = 0; mf < 4; ++mf) \
    _Pragma("unroll") for (int nf = 0; nf < 4; ++nf) \
        acc[mf][nf] = __builtin_amdgcn_mfma_f32_16x16x32_bf16(WF[nf], XF[mf], acc[mf][nf], 0, 0, 0); \
    __builtin_amdgcn_s_setprio(0); }

#define KSTEP(RD, SB, CX, CW, NX, NW, DOST, DOW, VMSTR) { \
    if (DOW) WLOAD(NW); \
    RDFRAG(RD, NX); \
    if (DOST) DO_STAGE(SB); \
    MFMACL(CX, CW); \
    asm volatile("s_waitcnt lgkmcnt(0)" ::: "memory"); \
    asm volatile("s_waitcnt " VMSTR ::: "memory"); \
    asm volatile("s_barrier" ::: "memory"); }

    // prologue: stage x(0),x(1),x(2) -> buf0,1,2 (6 loads); w(0) -> wa (4 loads)
    DO_STAGE(0); DO_STAGE(1); DO_STAGE(2);
    WLOAD(wa);
    asm volatile("s_waitcnt vmcnt(0)" ::: "memory"); // x(0..2), w(0) landed
    asm volatile("s_barrier" ::: "memory");
    RDFRAG(0, xa);                                   // frags x(0) -> regs
    asm volatile("s_waitcnt lgkmcnt(0)" ::: "memory");
    asm volatile("s_barrier" ::: "memory");          // all reads of buf0 retired

    for (int m = 0; m < 17; ++m) {      // k = 0..101
        KSTEP(1, 0, xa, wa, xb, wb, 1, 1, "vmcnt(2)");
        KSTEP(2, 1, xb, wb, xa, wa, 1, 1, "vmcnt(2)");
        KSTEP(0, 2, xa, wa, xb, wb, 1, 1, "vmcnt(2)");
        KSTEP(1, 0, xb, wb, xa, wa, 1, 1, "vmcnt(2)");
        KSTEP(2, 1, xa, wa, xb, wb, 1, 1, "vmcnt(2)");
        KSTEP(0, 2, xb, wb, xa, wa, 1, 1, "vmcnt(2)");
    }
    KSTEP(1, 0, xa, wa, xb, wb, 1, 1, "vmcnt(2)");   // k=102, st x(105), w(103)
    KSTEP(2, 1, xb, wb, xa, wa, 1, 1, "vmcnt(2)");   // k=103, st x(106), w(104)
    KSTEP(0, 2, xa, wa, xb, wb, 1, 1, "vmcnt(2)");   // k=104, st x(107), w(105)
    KSTEP(1, 0, xb, wb, xa, wa, 0, 1, "vmcnt(0)");   // k=105, w(106); drain
    KSTEP(2, 0, xa, wa, xb, wb, 0, 1, "vmcnt(0)");   // k=106, w(107); drain
    MFMACL(xb, wb);                                  // k=107

    // epilogue: bias + leaky_relu + sqrt(2) + clamp, direct stores
    const int pd = mslice >> 1, phb = (mslice & 1) * 2;
#pragma unroll
    for (int nf = 0; nf < 4; ++nf) {
        f32x4 bb = *(const f32x4*)&bias[ncol * 64 + nf * 16 + g * 4];
#pragma unroll
        for (int mf = 0; mf < 4; ++mf) {
            const int wq = (mf & 1) * 16 + ll;
            const int hh = h0 + phb + (mf >> 1);
            float* orow = out + ((size_t)(b * 128 + ncol * 64 + nf * 16 + g * 4) << 15)
                          + (d0 + pd) * 1024 + hh * 32 + wq;
#pragma unroll
            for (int q = 0; q < 4; ++q) {
                float v = acc[mf][nf][q] + bb[q];
                v = v > 0.f ? v : v * 0.2f;
                v *= 1.41421356237f;
                v = fminf(fmaxf(v, -256.f), 256.f);
                orow[(size_t)q << 15] = v;
            }
        }
    }
#undef WLOAD
#undef DO_STAGE
#undef RDFRAG
#undef MFMACL
#undef KSTEP
}

// ---------------- Fallback conv (R4, proven) if ws too small -----------------
#define NPOS 544
__global__ __launch_bounds__(256, 4) void conv_fb(
    const float* __restrict__ x, const u16* __restrict__ wn,
    const float* __restrict__ bias, float* __restrict__ out) {
    __shared__ __align__(16) u16 lds[NPOS * 32];
    float* ldsf = reinterpret_cast<float*>(lds);
    const int t = threadIdx.x;
    const int lane = t & 63;
    const int wid  = t >> 6;
    const int wr   = wid >> 1;
    const int wcn  = wid & 1;
    const int ll   = lane & 15;
    const int g    = lane >> 4;
    const int bid = blockIdx.x;
    const int b  = bid >> 8;
    const int dt = (bid >> 4) & 15, ht = bid & 15;
    const int d0 = dt * 2, h0 = ht * 2;
    const int sw  = t & 31;
    const int sg  = (t >> 5) & 3;
    const int rhi = t >> 7;
    f32x4 acc[4][4];
#pragma unroll
    for (int i = 0; i < 4; ++i)
#pragma unroll
        for (int j = 0; j < 4; ++j) acc[i][j] = (f32x4){0.f, 0.f, 0.f, 0.f};
    float bv[4][4];
#pragma unroll
    for (int nf = 0; nf < 4; ++nf) {
        f32x4 bb = *(const f32x4*)&bias[wcn * 64 + nf * 16 + g * 4];
#pragma unroll
        for (int q = 0; q < 4; ++q) bv[nf][q] = bb[q];
    }
    if (t < 128) {
        int pi  = t >> 2;
        int row = pi >> 1;
        int pos = row * 34 + (pi & 1) * 33;
        bf16x8 z = {0, 0, 0, 0, 0, 0, 0, 0};
        *(bf16x8*)&lds[pos * 32 + (t & 3) * 8] = z;
    }
    for (int c = 0; c < 4; ++c) {
        if (c) __syncthreads();
#pragma unroll
        for (int p = 0; p < 8; ++p) {
            int rowid = p * 2 + rhi;
            int pd = rowid >> 2, ph = rowid & 3;
            int d = d0 - 1 + pd, h = h0 - 1 + ph;
            bool ok = ((unsigned)d < 32u) && ((unsigned)h < 32u);
            const float* src = x + (((b * 128 + c * 32 + sg * 8) * 32 + d) * 32 + h) * 32 + sw;
            float v[8];
#pragma unroll
            for (int j = 0; j < 8; ++j) v[j] = ok ? src[j * 32768] : 0.f;
            bf16x8 pk;
#pragma unroll
            for (int j = 0; j < 8; ++j) pk[j] = (short)f2bf(v[j]);
            int pos = rowid * 34 + sw + 1;
            int sl = sg ^ ((pos >> 1) & 3);
            *(bf16x8*)&lds[pos * 32 + sl * 8] = pk;
        }
        __syncthreads();
        const u16* wbase = wn + c * 4096 + ((wcn * 64 + ll) * 32 + g * 8);
        bf16x8 wf[4];
#pragma unroll
        for (int nf = 0; nf < 4; ++nf) wf[nf] = *(const bf16x8*)&wbase[nf * 512];
#pragma unroll
        for (int tap = 0; tap < 27; ++tap) {
            const int od = tap / 9, oh = (tap / 3) % 3, ow = tap % 3;
            bf16x8 wfn[4];
            if (tap < 26) {
#pragma unroll
                for (int nf = 0; nf < 4; ++nf)
                    wfn[nf] = *(const bf16x8*)&wbase[(tap + 1) * 16384 + nf * 512];
            }
            bf16x8 xf[4];
#pragma unroll
            for (int mf = 0; mf < 4; ++mf) {
                int pos = ((wr + od) * 4 + (mf >> 1) + oh) * 34 + (mf & 1) * 16 + ll + ow;
                int sl = g ^ ((pos >> 1) & 3);
                xf[mf] = *(const bf16x8*)&lds[pos * 32 + sl * 8];
            }
            __builtin_amdgcn_s_setprio(1);
#pragma unroll
            for (int mf = 0; mf < 4; ++mf)
#pragma unroll
                for (int nf = 0; nf < 4; ++nf)
                    acc[mf][nf] = __builtin_amdgcn_mfma_f32_16x16x32_bf16(
                        wf[nf], xf[mf], acc[mf][nf], 0, 0, 0);
            __builtin_amdgcn_s_setprio(0);
            if (tap < 26) {
#pragma unroll
                for (int nf = 0; nf < 4; ++nf) wf[nf] = wfn[nf];
            }
        }
    }
#pragma unroll
    for (int p = 0; p < 4; ++p) {
        const int dd = p >> 1, hh = p & 1;
        __syncthreads();
        if (wr == dd) {
#pragma unroll
            for (int whalf = 0; whalf < 2; ++whalf) {
                const int mf = hh * 2 + whalf;
#pragma unroll
                for (int nf = 0; nf < 4; ++nf) {
#pragma unroll
                    for (int q = 0; q < 4; ++q) {
                        const int co = wcn * 64 + nf * 16 + g * 4 + q;
                        float v = acc[mf][nf][q] + bv[nf][q];
                        v = v > 0.f ? v : v * 0.2f;
                        v *= 1.41421356237f;
                        v = fminf(fmaxf(v, -256.f), 256.f);
                        ldsf[co * 33 + whalf * 16 + ll] = v;
                    }
                }
            }
        }
        __syncthreads();
#pragma unroll
        for (int it = 0; it < 4; ++it) {
            const int row = it * 32 + (t >> 3);
            const int ls  = t & 7;
            f32x4 v = *(f32x4*)&ldsf[row * 33 + ls * 4];
            *(f32x4*)&out[(size_t)(b * 128 + row) * 32768 +
                          (d0 + dd) * 1024 + (h0 + hh) * 32 + ls * 4] = v;
        }
    }
}

extern "C" void kernel_launch(void* const* d_in, const int* in_sizes, int n_in,
                              void* d_out, int out_size, void* d_ws, size_t ws_size,
                              hipStream_t stream) {
    const float* x    = (const float*)d_in[0];
    const float* w    = (const float*)d_in[1];
    const float* bias = (const float*)d_in[2];
    float* out        = (float*)d_out;
    u16* wsb          = (u16*)d_ws;

    hipMemsetAsync(d_ws, 0, 1024, stream);                 // zero page
    prep_w_k<<<128, 256, 0, stream>>>(w, wsb + 512);       // wn at +1KB

    if (ws_size >= 68157440ull) {
        xpose_k<<<8192, 256, 0, stream>>>(x, wsb + 524288);  // xt at +1MB
        conv_mx<<<1024, 512, 0, stream>>>(wsb, bias, out);
    } else {
        conv_fb<<<2048, 256, 0, stream>>>(x, wsb + 512, bias, out);
    }
}

// Round 13
// 382.202 us; speedup vs baseline: 1.3557x; 1.3557x over previous
//
#include <hip/hip_runtime.h>

typedef short bf16x8 __attribute__((ext_vector_type(8)));
typedef float f32x4  __attribute__((ext_vector_type(4)));
typedef unsigned short u16;

static __device__ __forceinline__ u16 f2bf(float f) {
    unsigned int u = __builtin_bit_cast(unsigned int, f);
    u += 0x7FFFu + ((u >> 16) & 1u);   // round-to-nearest-even
    return (u16)(u >> 16);
}

static __device__ __forceinline__ void gload_lds16(const void* g, void* l) {
    __builtin_amdgcn_global_load_lds((const __attribute__((address_space(1))) void*)g,
                                     (__attribute__((address_space(3))) void*)l, 16, 0, 0);
}

// ---------------- Kernel 1: demodulate + convert weights to bf16 -------------
// wn[((tap*4 + cc)*128 + co)*32 + ci_in_chunk]  == kstep-major [k108][co128][ci32]
__global__ __launch_bounds__(256) void prep_w_k(const float* __restrict__ w,
                                                u16* __restrict__ wn) {
    const int co = blockIdx.x;
    const int t  = threadIdx.x;
    const float* wc = w + co * 3456;
    float s = 0.f;
    for (int i = t; i < 3456; i += 256) { float v = wc[i]; s += v * v; }
#pragma unroll
    for (int off = 32; off; off >>= 1) s += __shfl_down(s, off);
    __shared__ float red[4];
    __shared__ float dsh;
    if ((t & 63) == 0) red[t >> 6] = s;
    __syncthreads();
    if (t == 0) dsh = rsqrtf(red[0] + red[1] + red[2] + red[3] + 1e-8f);
    __syncthreads();
    const float d = dsh;
    for (int i = t; i < 3456; i += 256) {
        int ci = i / 27, tap = i - ci * 27;
        float v = wc[i] * d;
        wn[((tap * 4 + (ci >> 5)) * 128 + co) * 32 + (ci & 31)] = f2bf(v);
    }
}

// ---------------- Kernel 2: transpose x -> channels-grouped bf16 -------------
// xt[((b*16 + g)*32768 + d*1024 + h*32 + w)*8 + j] = bf16(x[b][g*8+j][d][h][w])
__global__ __launch_bounds__(256) void xpose_k(const float* __restrict__ x,
                                               u16* __restrict__ xt) {
    const int bid = blockIdx.x;
    const int b = bid >> 10, d = (bid >> 5) & 31, h = bid & 31;
    const int t = threadIdx.x;
    const int w = t & 31, cg = t >> 5;
    const int base_dhw = d * 1024 + h * 32 + w;
#pragma unroll
    for (int r = 0; r < 2; ++r) {
        int g = cg + r * 8;
        const float* src = x + ((size_t)(b * 128 + g * 8) << 15) + base_dhw;
        bf16x8 pk;
#pragma unroll
        for (int j = 0; j < 8; ++j) pk[j] = (short)f2bf(src[(size_t)j << 15]);
        *(bf16x8*)&xt[((size_t)((b * 16 + g) << 15) + base_dhw) * 8] = pk;
    }
}

// ---------------- Kernel 3: conv3d — x global->reg dbuf, w ring-3 LDS --------
// 512 thr = 8 waves (4 M-slices x 2 co-halves). Tile M=256 (d2,h4,w32), N=128.
// (512,2): 256-VGPR budget, 8 waves/CU. LDS = w ring only: 3 x 8 KB = 24 KB.
// Per step k:
//   XLOAD x(k+1) global->reg (4x dwordx4, coalesced, zp-cndmask for halo)
//   WREAD w(k+1) from slot (k+1)%3 (4x ds_read_b128)
//   [sched_barrier] WSTAGE w(k+3) -> slot k%3 (1x global_load_lds)
//   MFMA frags(k) (all operands in regs)
//   lgkmcnt(0); vmcnt(1) [retire ws(k+2)+x(k+1); ws(k+3) flies]; s_barrier
// Pipes/CU/step: MFMA 621 cyc, LDS 40 KB, TA/L2 40 KB (unique-address).
#define KSX 1048576   // shorts: x advance per k-step (4 ci-groups * 32768 * 8)
#define KSW 4096      // shorts: wn advance per k-step
#define WRB 4096      // shorts: w ring stride (8 KB)
__global__ __launch_bounds__(512, 2) void conv_mx(
    const u16* __restrict__ wsb, const float* __restrict__ bias,
    float* __restrict__ out) {
    __shared__ __align__(16) u16 lds[3 * WRB];    // 24576 B
    const u16* xt = wsb + 524288;
    const u16* wn = wsb + 512;
    const u16* zp = wsb;                          // zero page (memset)

    const int t = threadIdx.x, lane = t & 63, wid = t >> 6;
    const int ll = lane & 15, g = lane >> 4;
    const int mslice = wid >> 1, ncol = wid & 1;

    int wg = ((blockIdx.x & 7) << 7) | (blockIdx.x >> 3);   // XCD swizzle
    const int b = wg >> 7, dt = (wg >> 3) & 15, ht = wg & 7;
    const int d0 = dt * 2, h0 = ht * 4;

    // w ds_read offset (loop-invariant, swizzled as staged)
    const int co0 = ncol * 64 + ll;
    const int wro = co0 * 32 + ((g ^ ((co0 >> 1) & 3)) * 8);

    // w staging lane constants (1 gload_lds per thread per k-step)
    const int wco = wid * 16 + (lane >> 2);
    const int slot = lane & 3;
    const u16* wsrc = wn + wco * 32 + ((slot ^ ((wco >> 1) & 3)) * 8);

    // x frag-row constants: rows mslice*2, mslice*2+1 of the 8-row tile
    const int pd0 = (mslice * 2) >> 2, ph0 = (mslice * 2) & 3;

    f32x4 acc[4][4];
#pragma unroll
    for (int i = 0; i < 4; ++i)
#pragma unroll
        for (int j = 0; j < 4; ++j) acc[i][j] = (f32x4){0.f, 0.f, 0.f, 0.f};

    // x cursor (tracks k+1 target of XLOAD; tap-major)
    int ccx = 0, owx = 0, ohx = 0, odx = 0;
    const u16* xb0 = xt; const u16* xb1 = xt;
    bool rok0 = false, rok1 = false, we0 = false, we1 = false;

    bf16x8 xa[4], wa[4], xb[4], wb[4];   // frag double-buffers

#define XLOAD(NX) { \
    if (ccx == 0) { \
        int Dx  = d0 + pd0 - 1 + odx; \
        int Hx0 = h0 + ph0 - 1 + ohx; \
        bool Dok = ((unsigned)Dx < 32u); \
        rok0 = Dok && ((unsigned)Hx0 < 32u); \
        rok1 = Dok && ((unsigned)(Hx0 + 1) < 32u); \
        xb0 = xt + (long)((b * 16 + g) * 32768 + Dx * 1024 + Hx0 * 32 + (owx - 1)) * 8; \
        xb1 = xb0 + 256; \
        we0 = (owx != 0) || (ll != 0); \
        we1 = (owx != 2) || (ll != 15); \
    } \
    const u16* p0 = (rok0 && we0) ? (xb0 + ll * 8)       : zp; \
    const u16* p1 = (rok0 && we1) ? (xb0 + 128 + ll * 8) : zp; \
    const u16* p2 = (rok1 && we0) ? (xb1 + ll * 8)       : zp; \
    const u16* p3 = (rok1 && we1) ? (xb1 + 128 + ll * 8) : zp; \
    NX[0] = *(const bf16x8*)p0; \
    NX[1] = *(const bf16x8*)p1; \
    NX[2] = *(const bf16x8*)p2; \
    NX[3] = *(const bf16x8*)p3; \
    xb0 += KSX; xb1 += KSX; \
    if (++ccx == 4) { ccx = 0; \
        if (++owx == 3) { owx = 0; if (++ohx == 3) { ohx = 0; ++odx; } } } }

#define WREAD(RD, WF) { \
    _Pragma("unroll") for (int nf = 0; nf < 4; ++nf) \
        WF[nf] = *(const bf16x8*)&lds[(RD)*WRB + wro + nf * 512]; }

#define WSTAGE(SB) { \
    gload_lds16((const void*)wsrc, (void*)&lds[(SB)*WRB + wid * 512]); \
    wsrc += KSW; }

#define MFMACL(XF, WF) { \
    __builtin_amdgcn_s_setprio(1); \
    _Pragma("unroll") for (int mf = 0; mf < 4; ++mf) \
    _Pragma("unroll") for (int nf = 0; nf < 4; ++nf) \
        acc[mf][nf] = __builtin_amdgcn_mfma_f32_16x16x32_bf16(WF[nf], XF[mf], acc[mf][nf], 0, 0, 0); \
    __builtin_amdgcn_s_setprio(0); }

#define KSTEP(RD, SB, CX, CW, NX, NW, DOST, VMSTR) { \
    XLOAD(NX); \
    WREAD(RD, NW); \
    __builtin_amdgcn_sched_barrier(0); \
    if (DOST) WSTAGE(SB); \
    MFMACL(CX, CW); \
    asm volatile("s_waitcnt lgkmcnt(0)" ::: "memory"); \
    asm volatile("s_waitcnt " VMSTR ::: "memory"); \
    asm volatile("s_barrier" ::: "memory"); }

    // prologue: stage w(0,1,2) -> slots 0,1,2; load x(0) -> xa; w(0) -> wa
    WSTAGE(0); WSTAGE(1); WSTAGE(2);
    XLOAD(xa);
    asm volatile("s_waitcnt vmcnt(0)" ::: "memory");  // w(0..2) in LDS, x(0) in regs
    asm volatile("s_barrier" ::: "memory");
    WREAD(0, wa);
    asm volatile("s_waitcnt lgkmcnt(0)" ::: "memory");
    asm volatile("s_barrier" ::: "memory");           // slot0 reads retired

    for (int m = 0; m < 17; ++m) {      // k = 0..101
        KSTEP(1, 0, xa, wa, xb, wb, 1, "vmcnt(1)");
        KSTEP(2, 1, xb, wb, xa, wa, 1, "vmcnt(1)");
        KSTEP(0, 2, xa, wa, xb, wb, 1, "vmcnt(1)");
        KSTEP(1, 0, xb, wb, xa, wa, 1, "vmcnt(1)");
        KSTEP(2, 1, xa, wa, xb, wb, 1, "vmcnt(1)");
        KSTEP(0, 2, xb, wb, xa, wa, 1, "vmcnt(1)");
    }
    KSTEP(1, 0, xa, wa, xb, wb, 1, "vmcnt(1)");     // k=102, stage w(105)
    KSTEP(2, 1, xb, wb, xa, wa, 1, "vmcnt(1)");     // k=103, stage w(106)
    KSTEP(0, 2, xa, wa, xb, wb, 1, "vmcnt(1)");     // k=104, stage w(107)
    KSTEP(1, 0, xb, wb, xa, wa, 0, "vmcnt(0)");     // k=105
    KSTEP(2, 0, xa, wa, xb, wb, 0, "vmcnt(0)");     // k=106
    MFMACL(xb, wb);                                  // k=107

    // epilogue: bias + leaky_relu + sqrt(2) + clamp, direct stores
    const int pd = mslice >> 1, phb = (mslice & 1) * 2;
#pragma unroll
    for (int nf = 0; nf < 4; ++nf) {
        f32x4 bb = *(const f32x4*)&bias[ncol * 64 + nf * 16 + g * 4];
#pragma unroll
        for (int mf = 0; mf < 4; ++mf) {
            const int wq = (mf & 1) * 16 + ll;
            const int hh = h0 + phb + (mf >> 1);
            float* orow = out + ((size_t)(b * 128 + ncol * 64 + nf * 16 + g * 4) << 15)
                          + (d0 + pd) * 1024 + hh * 32 + wq;
#pragma unroll
            for (int q = 0; q < 4; ++q) {
                float v = acc[mf][nf][q] + bb[q];
                v = v > 0.f ? v : v * 0.2f;
                v *= 1.41421356237f;
                v = fminf(fmaxf(v, -256.f), 256.f);
                orow[(size_t)q << 15] = v;
            }
        }
    }
#undef XLOAD
#undef WREAD
#undef WSTAGE
#undef MFMACL
#undef KSTEP
}

// ---------------- Fallback conv (R4, proven) if ws too small -----------------
#define NPOS 544
__global__ __launch_bounds__(256, 4) void conv_fb(
    const float* __restrict__ x, const u16* __restrict__ wn,
    const float* __restrict__ bias, float* __restrict__ out) {
    __shared__ __align__(16) u16 lds[NPOS * 32];
    float* ldsf = reinterpret_cast<float*>(lds);
    const int t = threadIdx.x;
    const int lane = t & 63;
    const int wid  = t >> 6;
    const int wr   = wid >> 1;
    const int wcn  = wid & 1;
    const int ll   = lane & 15;
    const int g    = lane >> 4;
    const int bid = blockIdx.x;
    const int b  = bid >> 8;
    const int dt = (bid >> 4) & 15, ht = bid & 15;
    const int d0 = dt * 2, h0 = ht * 2;
    const int sw  = t & 31;
    const int sg  = (t >> 5) & 3;
    const int rhi = t >> 7;
    f32x4 acc[4][4];
#pragma unroll
    for (int i = 0; i < 4; ++i)
#pragma unroll
        for (int j = 0; j < 4; ++j) acc[i][j] = (f32x4){0.f, 0.f, 0.f, 0.f};
    float bv[4][4];
#pragma unroll
    for (int nf = 0; nf < 4; ++nf) {
        f32x4 bb = *(const f32x4*)&bias[wcn * 64 + nf * 16 + g * 4];
#pragma unroll
        for (int q = 0; q < 4; ++q) bv[nf][q] = bb[q];
    }
    if (t < 128) {
        int pi  = t >> 2;
        int row = pi >> 1;
        int pos = row * 34 + (pi & 1) * 33;
        bf16x8 z = {0, 0, 0, 0, 0, 0, 0, 0};
        *(bf16x8*)&lds[pos * 32 + (t & 3) * 8] = z;
    }
    for (int c = 0; c < 4; ++c) {
        if (c) __syncthreads();
#pragma unroll
        for (int p = 0; p < 8; ++p) {
            int rowid = p * 2 + rhi;
            int pd = rowid >> 2, ph = rowid & 3;
            int d = d0 - 1 + pd, h = h0 - 1 + ph;
            bool ok = ((unsigned)d < 32u) && ((unsigned)h < 32u);
            const float* src = x + (((b * 128 + c * 32 + sg * 8) * 32 + d) * 32 + h) * 32 + sw;
            float v[8];
#pragma unroll
            for (int j = 0; j < 8; ++j) v[j] = ok ? src[j * 32768] : 0.f;
            bf16x8 pk;
#pragma unroll
            for (int j = 0; j < 8; ++j) pk[j] = (short)f2bf(v[j]);
            int pos = rowid * 34 + sw + 1;
            int sl = sg ^ ((pos >> 1) & 3);
            *(bf16x8*)&lds[pos * 32 + sl * 8] = pk;
        }
        __syncthreads();
        const u16* wbase = wn + c * 4096 + ((wcn * 64 + ll) * 32 + g * 8);
        bf16x8 wf[4];
#pragma unroll
        for (int nf = 0; nf < 4; ++nf) wf[nf] = *(const bf16x8*)&wbase[nf * 512];
#pragma unroll
        for (int tap = 0; tap < 27; ++tap) {
            const int od = tap / 9, oh = (tap / 3) % 3, ow = tap % 3;
            bf16x8 wfn[4];
            if (tap < 26) {
#pragma unroll
                for (int nf = 0; nf < 4; ++nf)
                    wfn[nf] = *(const bf16x8*)&wbase[(tap + 1) * 16384 + nf * 512];
            }
            bf16x8 xf[4];
#pragma unroll
            for (int mf = 0; mf < 4; ++mf) {
                int pos = ((wr + od) * 4 + (mf >> 1) + oh) * 34 + (mf & 1) * 16 + ll + ow;
                int sl = g ^ ((pos >> 1) & 3);
                xf[mf] = *(const bf16x8*)&lds[pos * 32 + sl * 8];
            }
            __builtin_amdgcn_s_setprio(1);
#pragma unroll
            for (int mf = 0; mf < 4; ++mf)
#pragma unroll
                for (int nf = 0; nf < 4; ++nf)
                    acc[mf][nf] = __builtin_amdgcn_mfma_f32_16x16x32_bf16(
                        wf[nf], xf[mf], acc[mf][nf], 0, 0, 0);
            __builtin_amdgcn_s_setprio(0);
            if (tap < 26) {
#pragma unroll
                for (int nf = 0; nf < 4; ++nf) wf[nf] = wfn[nf];
            }
        }
    }
#pragma unroll
    for (int p = 0; p < 4; ++p) {
        const int dd = p >> 1, hh = p & 1;
        __syncthreads();
        if (wr == dd) {
#pragma unroll
            for (int whalf = 0; whalf < 2; ++whalf) {
                const int mf = hh * 2 + whalf;
#pragma unroll
                for (int nf = 0; nf < 4; ++nf) {
#pragma unroll
                    for (int q = 0; q < 4; ++q) {
                        const int co = wcn * 64 + nf * 16 + g * 4 + q;
                        float v = acc[mf][nf][q] + bv[nf][q];
                        v = v > 0.f ? v : v * 0.2f;
                        v *= 1.41421356237f;
                        v = fminf(fmaxf(v, -256.f), 256.f);
                        ldsf[co * 33 + whalf * 16 + ll] = v;
                    }
                }
            }
        }
        __syncthreads();
#pragma unroll
        for (int it = 0; it < 4; ++it) {
            const int row = it * 32 + (t >> 3);
            const int ls  = t & 7;
            f32x4 v = *(f32x4*)&ldsf[row * 33 + ls * 4];
            *(f32x4*)&out[(size_t)(b * 128 + row) * 32768 +
                          (d0 + dd) * 1024 + (h0 + hh) * 32 + ls * 4] = v;
        }
    }
}

extern "C" void kernel_launch(void* const* d_in, const int* in_sizes, int n_in,
                              void* d_out, int out_size, void* d_ws, size_t ws_size,
                              hipStream_t stream) {
    const float* x    = (const float*)d_in[0];
    const float* w    = (const float*)d_in[1];
    const float* bias = (const float*)d_in[2];
    float* out        = (float*)d_out;
    u16* wsb          = (u16*)d_ws;

    hipMemsetAsync(d_ws, 0, 1024, stream);                 // zero page
    prep_w_k<<<128, 256, 0, stream>>>(w, wsb + 512);       // wn at +1KB

    if (ws_size >= 68157440ull) {
        xpose_k<<<8192, 256, 0, stream>>>(x, wsb + 524288);  // xt at +1MB
        conv_mx<<<1024, 512, 0, stream>>>(wsb, bias, out);
    } else {
        conv_fb<<<2048, 256, 0, stream>>>(x, wsb + 512, bias, out);
    }
}